// Round 10
// baseline (370.045 us; speedup 1.0000x reference)
//
#include <hip/hip_runtime.h>

typedef unsigned short u16;
typedef unsigned int u32;
typedef __bf16 bfrag __attribute__((ext_vector_type(8)));
typedef float f32x4 __attribute__((ext_vector_type(4)));
typedef float f32x2 __attribute__((ext_vector_type(2)));

__device__ __forceinline__ u16 f2bf(float f) {
    u32 u = __float_as_uint(f);
    u32 r = (u + 0x7FFFu + ((u >> 16) & 1u)) >> 16;
    return (u16)r;
}
__device__ __forceinline__ float bf2f(u32 h) {
    return __uint_as_float(h << 16);
}

// ---------------- combined: weight prepack + consts + bucket count/scan ----------------
// NOTE: ticket finalize is acceptable HERE because bcount blocks already end on a
// drain of their own histogram atomics; appending a __threadfence ticket to a kernel
// with fire-and-forget stores (mlp_pool, round 2) cost 330us. Don't repeat that.
__global__ __launch_bounds__(1024) void prepack_bcount_kernel(
    const int* __restrict__ dst, int* __restrict__ bcnt, int* __restrict__ done,
    int* __restrict__ bstart, int* __restrict__ bcur, int E, int nb, int nbc,
    const float* __restrict__ w11, const float* __restrict__ w12,
    const float* __restrict__ w21, const float* __restrict__ w22,
    u16* __restrict__ hi, u16* __restrict__ lo,
    const float* __restrict__ ne_b, const float* __restrict__ ee_w, const float* __restrict__ ee_b,
    const float* __restrict__ lin1_w, const float* __restrict__ lin1_b,
    const float* __restrict__ lin2_w, const float* __restrict__ lin2_b,
    float* __restrict__ u1, float* __restrict__ C1, float* __restrict__ u2, float* __restrict__ C2)
{
    if (blockIdx.x >= (u32)nbc) {
        int pb = blockIdx.x - nbc;
        if (pb == 64) {
            int c = threadIdx.x;
            if (c < 128) {
                float s1 = 0.f, t1 = 0.f, s2 = 0.f, t2 = 0.f;
                for (int k = 0; k < 128; ++k) {
                    float w1 = lin1_w[k * 128 + c];
                    float w2 = lin2_w[k * 128 + c];
                    float ew = ee_w[k], eb = ee_b[k];
                    s1 = fmaf(ew, w1, s1); t1 = fmaf(eb, w1, t1);
                    s2 = fmaf(ew, w2, s2); t2 = fmaf(eb, w2, t2);
                }
                u1[c] = s1; C1[c] = t1 + lin1_b[c] + ne_b[c];
                u2[c] = s2; C2[c] = t2 + lin2_b[c];
            }
            return;
        }
        int which = pb >> 4;
        const float* w = (which == 0) ? w11 : (which == 1) ? w12 : (which == 2) ? w21 : w22;
        int o = (pb & 15) * 1024 + threadIdx.x;   // 0..16383
        int j = o & 7;
        int lane = (o >> 3) & 63;
        int ct = (o >> 9) & 7;
        int ks = o >> 12;
        int k = ks * 32 + ((lane >> 4) * 8) + j;
        int c = ct * 16 + (lane & 15);
        float v = w[k * 128 + c];
        u16 h = f2bf(v);
        float vh = bf2f(h);
        u16 l = f2bf(v - vh);
        hi[which * 16384 + o] = h;
        lo[which * 16384 + o] = l;
        return;
    }

    // ---- bcount part ----
    __shared__ int h[256];
    __shared__ int is_last;
    if (threadIdx.x < 256) h[threadIdx.x] = 0;
    __syncthreads();
    int idx = blockIdx.x * 1024 + threadIdx.x;   // int4 index, covers 4 edges
    int e = idx * 4;
    if (e + 3 < E) {
        int4 d4 = ((const int4*)dst)[idx];
        atomicAdd(&h[d4.x >> 9], 1);
        atomicAdd(&h[d4.y >> 9], 1);
        atomicAdd(&h[d4.z >> 9], 1);
        atomicAdd(&h[d4.w >> 9], 1);
    } else {
        for (int k = e; k < E; ++k) atomicAdd(&h[dst[k] >> 9], 1);
    }
    __syncthreads();
    if (threadIdx.x < 256 && h[threadIdx.x]) atomicAdd(&bcnt[threadIdx.x], h[threadIdx.x]);
    __syncthreads();
    if (threadIdx.x == 0) {
        __threadfence();
        is_last = (atomicAdd(done, 1) == nbc - 1);
    }
    __syncthreads();
    if (!is_last) return;
    if (threadIdx.x < 256) h[threadIdx.x] = atomicAdd(&bcnt[threadIdx.x], 0);
    __syncthreads();
    __shared__ int excl[256];
    if (threadIdx.x < 64) {
        int l = threadIdx.x;
        int v0 = h[4 * l], v1 = h[4 * l + 1], v2 = h[4 * l + 2], v3 = h[4 * l + 3];
        int tot = v0 + v1 + v2 + v3;
        int run = tot;
#pragma unroll
        for (int off = 1; off < 64; off <<= 1) {
            int t = __shfl_up(run, off);
            if (l >= off) run += t;
        }
        int ex = run - tot;
        excl[4 * l] = ex;
        excl[4 * l + 1] = ex + v0;
        excl[4 * l + 2] = ex + v0 + v1;
        excl[4 * l + 3] = ex + v0 + v1 + v2;
    }
    __syncthreads();
    if (threadIdx.x < nb) {
        int ex = excl[threadIdx.x];
        bstart[threadIdx.x] = ex;
        bcur[threadIdx.x] = ex;
        if (threadIdx.x == nb - 1) bstart[nb] = ex + h[threadIdx.x];
    }
}

// block-local counting sort by bucket, coalesced run flush.
// record: x = src | (dst&511)<<17 (src < 2^17), y = attr bits
__global__ __launch_bounds__(1024) void bin_kernel(
    const int* __restrict__ src, const int* __restrict__ dst, const float* __restrict__ eattr,
    int* __restrict__ bucket_cursor,
    int2* __restrict__ binned, int E, int nb)
{
    __shared__ int hist[256];
    __shared__ int basel[256];
    __shared__ int gbase[256];
    __shared__ int2 stage[4096];
    __shared__ unsigned char sb[4096];
    const int tid = threadIdx.x;
    const int e0 = blockIdx.x * 4096;
    const int valid = min(4096, E - e0);

    if (tid < 256) hist[tid] = 0;
    __syncthreads();

    int d[4], s[4], a[4], rk[4];
    bool ok[4];
    const int eb = e0 + tid * 4;
    if (eb + 3 < E) {
        int4 d4 = *(const int4*)(dst + eb);
        int4 s4 = *(const int4*)(src + eb);
        int4 a4 = *(const int4*)((const int*)eattr + eb);
        d[0] = d4.x; d[1] = d4.y; d[2] = d4.z; d[3] = d4.w;
        s[0] = s4.x; s[1] = s4.y; s[2] = s4.z; s[3] = s4.w;
        a[0] = a4.x; a[1] = a4.y; a[2] = a4.z; a[3] = a4.w;
        ok[0] = ok[1] = ok[2] = ok[3] = true;
    } else {
#pragma unroll
        for (int k = 0; k < 4; ++k) {
            int e = eb + k;
            ok[k] = e < E;
            if (ok[k]) {
                d[k] = dst[e];
                s[k] = src[e];
                a[k] = __float_as_int(eattr[e]);
            }
        }
    }
#pragma unroll
    for (int k = 0; k < 4; ++k) {
        if (ok[k]) rk[k] = atomicAdd(&hist[d[k] >> 9], 1);
    }
    __syncthreads();
    if (tid < 64) {
        int l = tid;
        int v0 = hist[4 * l], v1 = hist[4 * l + 1], v2 = hist[4 * l + 2], v3 = hist[4 * l + 3];
        int tot = v0 + v1 + v2 + v3;
        int run = tot;
#pragma unroll
        for (int off = 1; off < 64; off <<= 1) {
            int t = __shfl_up(run, off);
            if (l >= off) run += t;
        }
        int ex = run - tot;
        basel[4 * l] = ex;
        basel[4 * l + 1] = ex + v0;
        basel[4 * l + 2] = ex + v0 + v1;
        basel[4 * l + 3] = ex + v0 + v1 + v2;
    }
    __syncthreads();
    if (tid < nb && hist[tid] > 0) gbase[tid] = atomicAdd(&bucket_cursor[tid], hist[tid]);
#pragma unroll
    for (int k = 0; k < 4; ++k) {
        if (ok[k]) {
            int b = d[k] >> 9;
            int pos = basel[b] + rk[k];
            stage[pos] = make_int2(s[k] | ((d[k] & 511) << 17), a[k]);
            sb[pos] = (unsigned char)b;
        }
    }
    __syncthreads();
    for (int i = tid; i < valid; i += 1024) {
        int b = (int)sb[i];
        binned[gbase[b] + (i - basel[b])] = stage[i];
    }
}

// One block per bucket: LDS histogram by dlo -> rowptr slice -> cursor scatter
__global__ __launch_bounds__(1024) void fine_kernel(
    const int2* __restrict__ binned, const int* __restrict__ bstart,
    int* __restrict__ rowptr, int2* __restrict__ edges, int N, int nbuckets)
{
    __shared__ int hist[512];
    __shared__ int excl[512];
    const int tid = threadIdx.x;
    const int b = blockIdx.x;
    const int s0 = bstart[b], s1 = bstart[b + 1];
    if (tid < 512) hist[tid] = 0;
    __syncthreads();
    for (int i = s0 + tid; i < s1; i += 1024)
        atomicAdd(&hist[(binned[i].x >> 17) & 511], 1);
    __syncthreads();
    if (tid < 64) {
        int l = tid;
        int v[8], pre[8];
        int tot = 0;
#pragma unroll
        for (int k = 0; k < 8; ++k) { v[k] = hist[8 * l + k]; pre[k] = tot; tot += v[k]; }
        int run = tot;
#pragma unroll
        for (int off = 1; off < 64; off <<= 1) {
            int t = __shfl_up(run, off);
            if (l >= off) run += t;
        }
        int ex = run - tot;
#pragma unroll
        for (int k = 0; k < 8; ++k) excl[8 * l + k] = ex + pre[k];
    }
    __syncthreads();
    const int nbase = b << 9;
    if (tid < 512 && nbase + tid < N) rowptr[nbase + tid] = s0 + excl[tid];
    if (b == nbuckets - 1 && tid == 0) rowptr[N] = s1;
    __syncthreads();
    for (int i = s0 + tid; i < s1; i += 1024) {
        int2 ed = binned[i];
        int dlo = (ed.x >> 17) & 511;
        ed.x &= 0x1FFFF;
        int pos = atomicAdd(&excl[dlo], 1);
        edges[s0 + pos] = ed;
    }
}

// ---------------- pull aggregation ----------------
// NOTE: pull kernels must stay separate from the MFMA MLP kernels (unified VGPR/AGPR
// file: fused kernel capped occupancy, BW 2.7 -> 1.17 TB/s, round 1).
//
// Round-10 layout: HALF-WAVE DUAL-CHAIN. chain0 = lanes 0-31, chain1 = lanes 32-63;
// each lane owns 4 channels (8B) of its chain's 256B row. One dwordx2 gather per
// step covers BOTH chains' edges; edge records are loaded per-lane (half-broadcast)
// so av/src need ZERO readlanes. Same 8-deep per chain (depth proven in round 5;
// deeper spills, rounds 6/7). Per-channel accumulation order identical to round 9
// (same edge sequence) -> bit-identical output. FETCH floor 192 MB unchanged.

__device__ __forceinline__ f32x4 bf4(uint2 hv) {
    f32x4 r;
    r[0] = __uint_as_float(hv.x << 16);
    r[1] = __uint_as_float(hv.x & 0xFFFF0000u);
    r[2] = __uint_as_float(hv.y << 16);
    r[3] = __uint_as_float(hv.y & 0xFFFF0000u);
    return r;
}

// pull1 batch: 8 edges of one chain (jb per-lane: j0 for lanes<32, j1 for >=32)
__device__ __forceinline__ void p1_any8(
    const float* __restrict__ x, const int2* __restrict__ edges, int jb,
    f32x4 A, f32x4 Bv, f32x4 Cv, bool act, f32x4& acc)
{
    int2 ep[8];
    float xs[8];
#pragma unroll
    for (int t = 0; t < 8; ++t) ep[t] = edges[jb + t];
#pragma unroll
    for (int t = 0; t < 8; ++t)
        xs[t] = *(const float*)((const char*)x + (((u32)ep[t].x) << 2));
    const f32x4 zero = {0.f, 0.f, 0.f, 0.f};
#pragma unroll
    for (int t = 0; t < 8; ++t) {
        float av = __int_as_float(ep[t].y);
        f32x4 m = __builtin_elementwise_fma((f32x4){xs[t], xs[t], xs[t], xs[t]}, A,
                    __builtin_elementwise_fma((f32x4){av, av, av, av}, Bv, Cv));
        m = __builtin_elementwise_max(m, zero);
        if (act) acc += m;
    }
}

__global__ __launch_bounds__(256) void pull1_kernel(
    const float* __restrict__ x,
    const int* __restrict__ rowptr, const int2* __restrict__ edges,
    const float* __restrict__ ne_w, const float* __restrict__ ne_b,
    const float* __restrict__ u1, const float* __restrict__ C1,
    u16* __restrict__ zb, int N)
{
    const int lane = threadIdx.x & 63;
    const int half = lane >> 5;
    const int cl = lane & 31;            // channel-lane: owns channels [cl*4, cl*4+4)
    const u32 loff = (u32)cl * 8u;
    int pair = blockIdx.x * 4 + (threadIdx.x >> 6);
    int n0 = pair * 2;
    if (n0 >= N) return;
    const bool has1 = (n0 + 1 < N);
    f32x4 A   = *(const f32x4*)(ne_w + cl * 4);
    f32x4 Bv  = *(const f32x4*)(u1   + cl * 4);
    f32x4 Cv  = *(const f32x4*)(C1   + cl * 4);
    f32x4 nbv = *(const f32x4*)(ne_b + cl * 4);
    const f32x4 zero = {0.f, 0.f, 0.f, 0.f};
    int j0  = rowptr[n0];
    int je0 = rowptr[n0 + 1];
    int j1  = je0;
    int je1 = has1 ? rowptr[n0 + 2] : je0;
    const int nself = half ? (has1 ? n0 + 1 : n0) : n0;
    float xn = x[nself];
    f32x4 acc = zero;
    while (j0 + 8 <= je0 && j1 + 8 <= je1) {
        int jb = half ? j1 : j0;
        p1_any8(x, edges, jb, A, Bv, Cv, true, acc);
        j0 += 8; j1 += 8;
    }
    while (j0 + 8 <= je0) { p1_any8(x, edges, j0, A, Bv, Cv, half == 0, acc); j0 += 8; }
    while (j1 + 8 <= je1) { p1_any8(x, edges, j1, A, Bv, Cv, half == 1, acc); j1 += 8; }
    for (; j0 < je0; ++j0) {
        int2 ep = edges[j0];
        float xs = *(const float*)((const char*)x + (((u32)ep.x) << 2));
        float av = __int_as_float(ep.y);
        f32x4 m = __builtin_elementwise_fma((f32x4){xs, xs, xs, xs}, A,
                    __builtin_elementwise_fma((f32x4){av, av, av, av}, Bv, Cv));
        m = __builtin_elementwise_max(m, zero);
        if (half == 0) acc += m;
    }
    for (; j1 < je1; ++j1) {
        int2 ep = edges[j1];
        float xs = *(const float*)((const char*)x + (((u32)ep.x) << 2));
        float av = __int_as_float(ep.y);
        f32x4 m = __builtin_elementwise_fma((f32x4){xs, xs, xs, xs}, A,
                    __builtin_elementwise_fma((f32x4){av, av, av, av}, Bv, Cv));
        m = __builtin_elementwise_max(m, zero);
        if (half == 1) acc += m;
    }
    f32x4 z = __builtin_elementwise_fma((f32x4){xn, xn, xn, xn}, A, nbv) + acc;
    uint2 outp;
    outp.x = (u32)f2bf(z[0]) | ((u32)f2bf(z[1]) << 16);
    outp.y = (u32)f2bf(z[2]) | ((u32)f2bf(z[3]) << 16);
    if (half == 0 || has1)
        *(uint2*)((char*)zb + (((u32)nself) << 8) + loff) = outp;
}

// pull2 batch: 8 edges of one chain, 8B (4ch) gather per lane
__device__ __forceinline__ void p2_any8(
    const u16* __restrict__ h1b, const int2* __restrict__ edges, int jb, u32 loff,
    f32x4 Bv, f32x4 Cv, bool act, f32x4& acc)
{
    int2 ep[8];
    uint2 hv[8];
#pragma unroll
    for (int t = 0; t < 8; ++t) ep[t] = edges[jb + t];
#pragma unroll
    for (int t = 0; t < 8; ++t)
        hv[t] = *(const uint2*)((const char*)h1b + ((((u32)ep[t].x) << 8) | loff));
    const f32x4 zero = {0.f, 0.f, 0.f, 0.f};
#pragma unroll
    for (int t = 0; t < 8; ++t) {
        float av = __int_as_float(ep[t].y);
        f32x4 m = bf4(hv[t]) + __builtin_elementwise_fma((f32x4){av, av, av, av}, Bv, Cv);
        m = __builtin_elementwise_max(m, zero);
        if (act) acc += m;
    }
}

__global__ __launch_bounds__(256) void pull2_kernel(
    const u16* __restrict__ h1b,
    const int* __restrict__ rowptr, const int2* __restrict__ edges,
    const float* __restrict__ u2, const float* __restrict__ C2,
    u16* __restrict__ zb2, int N)
{
    const int lane = threadIdx.x & 63;
    const int half = lane >> 5;
    const int cl = lane & 31;
    const u32 loff = (u32)cl * 8u;
    int pair = blockIdx.x * 4 + (threadIdx.x >> 6);
    int n0 = pair * 2;
    if (n0 >= N) return;
    const bool has1 = (n0 + 1 < N);
    f32x4 Bv = *(const f32x4*)(u2 + cl * 4);
    f32x4 Cv = *(const f32x4*)(C2 + cl * 4);
    const f32x4 zero = {0.f, 0.f, 0.f, 0.f};
    int j0  = rowptr[n0];
    int je0 = rowptr[n0 + 1];
    int j1  = je0;
    int je1 = has1 ? rowptr[n0 + 2] : je0;
    const int nself = half ? (has1 ? n0 + 1 : n0) : n0;
    uint2 hnp = *(const uint2*)((const char*)h1b + (((u32)nself << 8) | loff));
    f32x4 acc = zero;
    while (j0 + 8 <= je0 && j1 + 8 <= je1) {
        int jb = half ? j1 : j0;
        p2_any8(h1b, edges, jb, loff, Bv, Cv, true, acc);
        j0 += 8; j1 += 8;
    }
    while (j0 + 8 <= je0) { p2_any8(h1b, edges, j0, loff, Bv, Cv, half == 0, acc); j0 += 8; }
    while (j1 + 8 <= je1) { p2_any8(h1b, edges, j1, loff, Bv, Cv, half == 1, acc); j1 += 8; }
    for (; j0 < je0; ++j0) {
        int2 ep = edges[j0];
        uint2 hv = *(const uint2*)((const char*)h1b + ((((u32)ep.x) << 8) | loff));
        float av = __int_as_float(ep.y);
        f32x4 m = bf4(hv) + __builtin_elementwise_fma((f32x4){av, av, av, av}, Bv, Cv);
        m = __builtin_elementwise_max(m, zero);
        if (half == 0) acc += m;
    }
    for (; j1 < je1; ++j1) {
        int2 ep = edges[j1];
        uint2 hv = *(const uint2*)((const char*)h1b + ((((u32)ep.x) << 8) | loff));
        float av = __int_as_float(ep.y);
        f32x4 m = bf4(hv) + __builtin_elementwise_fma((f32x4){av, av, av, av}, Bv, Cv);
        m = __builtin_elementwise_max(m, zero);
        if (half == 1) acc += m;
    }
    f32x4 z = bf4(hnp) + acc;
    uint2 outp;
    outp.x = (u32)f2bf(z[0]) | ((u32)f2bf(z[1]) << 16);
    outp.y = (u32)f2bf(z[2]) | ((u32)f2bf(z[3]) << 16);
    if (half == 0 || has1)
        *(uint2*)((char*)zb2 + (((u32)nself) << 8) + loff) = outp;
}

// ---------------- fused 2-GEMM node MLP (bf16 MFMA, split weights) ----------------
// Round-9 geometry: wave = 64 rows x 2 ct. Each bh/bl load feeds 8 MFMAs ->
// weight traffic 200 MB total across both MLP kernels (was 800). Accumulation
// order per output element unchanged (ks-outer, hi->lo) -> bit-identical.
__global__ __launch_bounds__(256) void mlp_kernel(
    const u16* __restrict__ zb,
    const u16* __restrict__ w1hi, const u16* __restrict__ w1lo,
    const u16* __restrict__ w2hi, const u16* __restrict__ w2lo,
    const float* __restrict__ b1, const float* __restrict__ b2,
    u16* __restrict__ outb)
{
    __shared__ __align__(16) u16 tls[64][136];
    const int lane = threadIdx.x & 63;
    const int wv = threadIdx.x >> 6;
    const int m = lane & 15;
    const int q = lane >> 4;
    const int ko = q * 8;
    const long base_row = (long)blockIdx.x * 64;
    const int ct0 = wv * 2;

    f32x4 acc[2][4];
#pragma unroll
    for (int c = 0; c < 2; ++c)
#pragma unroll
        for (int g = 0; g < 4; ++g) acc[c][g] = (f32x4){0.f, 0.f, 0.f, 0.f};

#pragma unroll
    for (int ks = 0; ks < 4; ++ks) {
        bfrag a[4];
#pragma unroll
        for (int g = 0; g < 4; ++g)
            a[g] = *(const bfrag*)(zb + (base_row + g * 16 + m) * 128 + ks * 32 + ko);
#pragma unroll
        for (int c = 0; c < 2; ++c) {
            const int off = (((ks * 8 + ct0 + c) * 64) + lane) * 8;
            bfrag bh = *(const bfrag*)(w1hi + off);
            bfrag bl = *(const bfrag*)(w1lo + off);
#pragma unroll
            for (int g = 0; g < 4; ++g)
                acc[c][g] = __builtin_amdgcn_mfma_f32_16x16x32_bf16(a[g], bh, acc[c][g], 0, 0, 0);
#pragma unroll
            for (int g = 0; g < 4; ++g)
                acc[c][g] = __builtin_amdgcn_mfma_f32_16x16x32_bf16(a[g], bl, acc[c][g], 0, 0, 0);
        }
    }
#pragma unroll
    for (int c = 0; c < 2; ++c) {
        float bv = b1[(ct0 + c) * 16 + m];
#pragma unroll
        for (int g = 0; g < 4; ++g)
#pragma unroll
            for (int r = 0; r < 4; ++r) {
                float v = fmaxf(acc[c][g][r] + bv, 0.f);
                tls[g * 16 + q * 4 + r][(ct0 + c) * 16 + m] = f2bf(v);
            }
    }
    __syncthreads();

    f32x4 acc2[2][4];
#pragma unroll
    for (int c = 0; c < 2; ++c)
#pragma unroll
        for (int g = 0; g < 4; ++g) acc2[c][g] = (f32x4){0.f, 0.f, 0.f, 0.f};

#pragma unroll
    for (int ks = 0; ks < 4; ++ks) {
        bfrag a[4];
#pragma unroll
        for (int g = 0; g < 4; ++g)
            a[g] = *(const bfrag*)(&tls[g * 16 + m][ks * 32 + ko]);
#pragma unroll
        for (int c = 0; c < 2; ++c) {
            const int off = (((ks * 8 + ct0 + c) * 64) + lane) * 8;
            bfrag bh = *(const bfrag*)(w2hi + off);
            bfrag bl = *(const bfrag*)(w2lo + off);
#pragma unroll
            for (int g = 0; g < 4; ++g)
                acc2[c][g] = __builtin_amdgcn_mfma_f32_16x16x32_bf16(a[g], bh, acc2[c][g], 0, 0, 0);
#pragma unroll
            for (int g = 0; g < 4; ++g)
                acc2[c][g] = __builtin_amdgcn_mfma_f32_16x16x32_bf16(a[g], bl, acc2[c][g], 0, 0, 0);
        }
    }
    __syncthreads();   // all waves done reading tls before overwrite
#pragma unroll
    for (int c = 0; c < 2; ++c) {
        float bv = b2[(ct0 + c) * 16 + m];
#pragma unroll
        for (int g = 0; g < 4; ++g)
#pragma unroll
            for (int r = 0; r < 4; ++r) {
                float v = fmaxf(acc2[c][g][r] + bv, 0.f);
                tls[g * 16 + q * 4 + r][(ct0 + c) * 16 + m] = f2bf(v);
            }
    }
    __syncthreads();
#pragma unroll
    for (int it = 0; it < 4; ++it) {
        int chunk = threadIdx.x + it * 256;   // 0..1023
        int row = chunk >> 4;
        int c8 = (chunk & 15) * 8;
        *(uint4*)(outb + (base_row + row) * 128 + c8) = *(const uint4*)(&tls[row][c8]);
    }
}

// Same MLP but final layer: no h2 global write — pool directly from LDS.
// Fire-and-forget pool atomics; blocks retire without draining (do NOT add a ticket here).
__global__ __launch_bounds__(256) void mlp_pool_kernel(
    const u16* __restrict__ zb,
    const u16* __restrict__ w1hi, const u16* __restrict__ w1lo,
    const u16* __restrict__ w2hi, const u16* __restrict__ w2lo,
    const float* __restrict__ b1, const float* __restrict__ b2,
    const int* __restrict__ batch, float* __restrict__ poolacc, int N)
{
    __shared__ __align__(16) u16 tls[64][136];
    __shared__ int bsh[64];
    const int lane = threadIdx.x & 63;
    const int wv = threadIdx.x >> 6;
    const int m = lane & 15;
    const int q = lane >> 4;
    const int ko = q * 8;
    const long base_row = (long)blockIdx.x * 64;
    const int ct0 = wv * 2;

    if (threadIdx.x < 64) {
        long node = base_row + threadIdx.x;
        bsh[threadIdx.x] = (node < N) ? batch[node] : -1;
    }

    f32x4 acc[2][4];
#pragma unroll
    for (int c = 0; c < 2; ++c)
#pragma unroll
        for (int g = 0; g < 4; ++g) acc[c][g] = (f32x4){0.f, 0.f, 0.f, 0.f};

#pragma unroll
    for (int ks = 0; ks < 4; ++ks) {
        bfrag a[4];
#pragma unroll
        for (int g = 0; g < 4; ++g)
            a[g] = *(const bfrag*)(zb + (base_row + g * 16 + m) * 128 + ks * 32 + ko);
#pragma unroll
        for (int c = 0; c < 2; ++c) {
            const int off = (((ks * 8 + ct0 + c) * 64) + lane) * 8;
            bfrag bh = *(const bfrag*)(w1hi + off);
            bfrag bl = *(const bfrag*)(w1lo + off);
#pragma unroll
            for (int g = 0; g < 4; ++g)
                acc[c][g] = __builtin_amdgcn_mfma_f32_16x16x32_bf16(a[g], bh, acc[c][g], 0, 0, 0);
#pragma unroll
            for (int g = 0; g < 4; ++g)
                acc[c][g] = __builtin_amdgcn_mfma_f32_16x16x32_bf16(a[g], bl, acc[c][g], 0, 0, 0);
        }
    }
#pragma unroll
    for (int c = 0; c < 2; ++c) {
        float bv = b1[(ct0 + c) * 16 + m];
#pragma unroll
        for (int g = 0; g < 4; ++g)
#pragma unroll
            for (int r = 0; r < 4; ++r) {
                float v = fmaxf(acc[c][g][r] + bv, 0.f);
                tls[g * 16 + q * 4 + r][(ct0 + c) * 16 + m] = f2bf(v);
            }
    }
    __syncthreads();

    f32x4 acc2[2][4];
#pragma unroll
    for (int c = 0; c < 2; ++c)
#pragma unroll
        for (int g = 0; g < 4; ++g) acc2[c][g] = (f32x4){0.f, 0.f, 0.f, 0.f};

#pragma unroll
    for (int ks = 0; ks < 4; ++ks) {
        bfrag a[4];
#pragma unroll
        for (int g = 0; g < 4; ++g)
            a[g] = *(const bfrag*)(&tls[g * 16 + m][ks * 32 + ko]);
#pragma unroll
        for (int c = 0; c < 2; ++c) {
            const int off = (((ks * 8 + ct0 + c) * 64) + lane) * 8;
            bfrag bh = *(const bfrag*)(w2hi + off);
            bfrag bl = *(const bfrag*)(w2lo + off);
#pragma unroll
            for (int g = 0; g < 4; ++g)
                acc2[c][g] = __builtin_amdgcn_mfma_f32_16x16x32_bf16(a[g], bh, acc2[c][g], 0, 0, 0);
#pragma unroll
            for (int g = 0; g < 4; ++g)
                acc2[c][g] = __builtin_amdgcn_mfma_f32_16x16x32_bf16(a[g], bl, acc2[c][g], 0, 0, 0);
        }
    }
    __syncthreads();   // tls reuse
#pragma unroll
    for (int c = 0; c < 2; ++c) {
        float bv = b2[(ct0 + c) * 16 + m];
#pragma unroll
        for (int g = 0; g < 4; ++g)
#pragma unroll
            for (int r = 0; r < 4; ++r) {
                float v = fmaxf(acc2[c][g][r] + bv, 0.f);
                tls[g * 16 + q * 4 + r][(ct0 + c) * 16 + m] = f2bf(v);
            }
    }
    __syncthreads();

    int c = threadIdx.x & 127;
    int half = threadIdx.x >> 7;
    int r0 = half * 32, r1 = r0 + 32;
    int cur = -1;
    float sum = 0.f;
    for (int r = r0; r < r1; ++r) {
        int g = bsh[r];
        if (g < 0) break;
        float v = bf2f((u32)tls[r][c]);
        if (g != cur) {
            if (cur >= 0) atomicAdd(&poolacc[cur * 128 + c], sum);
            sum = 0.f;
            cur = g;
        }
        sum += v;
    }
    if (cur >= 0) atomicAdd(&poolacc[cur * 128 + c], sum);
}

// divide by per-graph counts (binary search in sorted batch)
__global__ __launch_bounds__(128) void pool2_kernel(
    const float* __restrict__ acc, const int* __restrict__ batch,
    float* __restrict__ out, int n)
{
    int g = blockIdx.x;
    int c = threadIdx.x;
    int lo = 0, hi = n;
    while (lo < hi) { int mid = (lo + hi) >> 1; if (batch[mid] < g) lo = mid + 1; else hi = mid; }
    int s = lo;
    lo = s; hi = n;
    while (lo < hi) { int mid = (lo + hi) >> 1; if (batch[mid] < g + 1) lo = mid + 1; else hi = mid; }
    int cnt = lo - s;
    out[g * 128 + c] = acc[g * 128 + c] / (float)(cnt > 0 ? cnt : 1);
}

// ---------------- launch ----------------
extern "C" void kernel_launch(void* const* d_in, const int* in_sizes, int n_in,
                              void* d_out, int out_size, void* d_ws, size_t ws_size,
                              hipStream_t stream)
{
    const float* x      = (const float*)d_in[0];
    const int*   ei     = (const int*)d_in[1];
    const float* eattr  = (const float*)d_in[2];
    const int*   batch  = (const int*)d_in[3];
    const float* ne_w   = (const float*)d_in[4];
    const float* ne_b   = (const float*)d_in[5];
    const float* ee_w   = (const float*)d_in[6];
    const float* ee_b   = (const float*)d_in[7];
    const float* lin1_w = (const float*)d_in[8];
    const float* lin1_b = (const float*)d_in[9];
    const float* w11    = (const float*)d_in[10];
    const float* b11    = (const float*)d_in[11];
    const float* w12    = (const float*)d_in[12];
    const float* b12    = (const float*)d_in[13];
    const float* lin2_w = (const float*)d_in[14];
    const float* lin2_b = (const float*)d_in[15];
    const float* w21    = (const float*)d_in[16];
    const float* b21    = (const float*)d_in[17];
    const float* w22    = (const float*)d_in[18];
    const float* b22    = (const float*)d_in[19];

    const int N = in_sizes[0];
    const int E = in_sizes[2];
    const int G = out_size / 128;
    const int Npad = ((N + 63) / 64) * 64;
    const int nb = (N + 511) >> 9;     // 512-node buckets (<=256)
    const int nbc = (E + 4095) / 4096; // bcount/bin grid over edges
    const int* esrc = ei;
    const int* edst = ei + E;

    char* p = (char*)d_ws;
    auto alloc = [&](size_t bytes) -> void* {
        void* r = (void*)p;
        p += (bytes + 255) & ~(size_t)255;
        return r;
    };
    float* u1 = (float*)alloc(128 * 4);
    float* C1 = (float*)alloc(128 * 4);
    float* u2 = (float*)alloc(128 * 4);
    float* C2 = (float*)alloc(128 * 4);
    int* bcnt   = (int*)alloc(1024);
    int* done   = (int*)alloc(256);
    float* poolacc = (float*)alloc((size_t)G * 128 * 4);
    int* bstart = (int*)alloc(((size_t)nb + 1) * 4);
    int* bcur   = (int*)alloc((size_t)nb * 4);
    int* rowptr = (int*)alloc(((size_t)N + 1) * 4);
    int2* edges = (int2*)alloc((size_t)E * 8);
    int2* binned = (int2*)alloc((size_t)E * 8);
    u16* whi = (u16*)alloc((size_t)4 * 16384 * 2);
    u16* wlo = (u16*)alloc((size_t)4 * 16384 * 2);
    u16* bufA = (u16*)alloc((size_t)Npad * 128 * 2);
    u16* bufB = (u16*)alloc((size_t)Npad * 128 * 2);

    // one memset covers bcnt..done..poolacc (adjacent allocations)
    size_t zbytes = (size_t)((char*)poolacc + (size_t)G * 128 * 4 - (char*)bcnt);
    hipMemsetAsync(bcnt, 0, zbytes, stream);

    prepack_bcount_kernel<<<nbc + 65, 1024, 0, stream>>>(
        edst, bcnt, done, bstart, bcur, E, nb, nbc,
        w11, w12, w21, w22, whi, wlo,
        ne_b, ee_w, ee_b, lin1_w, lin1_b, lin2_w, lin2_b, u1, C1, u2, C2);

    bin_kernel<<<nbc, 1024, 0, stream>>>(esrc, edst, eattr, bcur, binned, E, nb);
    fine_kernel<<<nb, 1024, 0, stream>>>(binned, bstart, rowptr, edges, N, nb);

    pull1_kernel<<<(N + 7) / 8, 256, 0, stream>>>(x, rowptr, edges, ne_w, ne_b, u1, C1,
                                                  bufA, N);
    mlp_kernel<<<Npad / 64, 256, 0, stream>>>(bufA, whi, wlo, whi + 16384, wlo + 16384,
                                              b11, b12, bufB);
    pull2_kernel<<<(N + 7) / 8, 256, 0, stream>>>(bufB, rowptr, edges, u2, C2, bufA, N);
    mlp_pool_kernel<<<Npad / 64, 256, 0, stream>>>(bufA, whi + 32768, wlo + 32768,
                                                   whi + 49152, wlo + 49152, b21, b22,
                                                   batch, poolacc, N);

    pool2_kernel<<<G, 128, 0, stream>>>(poolacc, batch, (float*)d_out, N);
}

// Round 11
// 318.877 us; speedup vs baseline: 1.1605x; 1.1605x over previous
//
#include <hip/hip_runtime.h>

typedef unsigned short u16;
typedef unsigned int u32;
typedef __bf16 bfrag __attribute__((ext_vector_type(8)));
typedef float f32x4 __attribute__((ext_vector_type(4)));
typedef float f32x2 __attribute__((ext_vector_type(2)));

__device__ __forceinline__ u16 f2bf(float f) {
    u32 u = __float_as_uint(f);
    u32 r = (u + 0x7FFFu + ((u >> 16) & 1u)) >> 16;
    return (u16)r;
}
__device__ __forceinline__ float bf2f(u32 h) {
    return __uint_as_float(h << 16);
}

// ---------------- combined: weight prepack + consts + bucket count/scan ----------------
// NOTE: ticket finalize is acceptable HERE because bcount blocks already end on a
// drain of their own histogram atomics; appending a __threadfence ticket to a kernel
// with fire-and-forget stores (mlp_pool, round 2) cost 330us. Don't repeat that.
__global__ __launch_bounds__(1024) void prepack_bcount_kernel(
    const int* __restrict__ dst, int* __restrict__ bcnt, int* __restrict__ done,
    int* __restrict__ bstart, int* __restrict__ bcur, int E, int nb, int nbc,
    const float* __restrict__ w11, const float* __restrict__ w12,
    const float* __restrict__ w21, const float* __restrict__ w22,
    u16* __restrict__ hi, u16* __restrict__ lo,
    const float* __restrict__ ne_b, const float* __restrict__ ee_w, const float* __restrict__ ee_b,
    const float* __restrict__ lin1_w, const float* __restrict__ lin1_b,
    const float* __restrict__ lin2_w, const float* __restrict__ lin2_b,
    float* __restrict__ u1, float* __restrict__ C1, float* __restrict__ u2, float* __restrict__ C2)
{
    if (blockIdx.x >= (u32)nbc) {
        int pb = blockIdx.x - nbc;
        if (pb == 64) {
            int c = threadIdx.x;
            if (c < 128) {
                float s1 = 0.f, t1 = 0.f, s2 = 0.f, t2 = 0.f;
                for (int k = 0; k < 128; ++k) {
                    float w1 = lin1_w[k * 128 + c];
                    float w2 = lin2_w[k * 128 + c];
                    float ew = ee_w[k], eb = ee_b[k];
                    s1 = fmaf(ew, w1, s1); t1 = fmaf(eb, w1, t1);
                    s2 = fmaf(ew, w2, s2); t2 = fmaf(eb, w2, t2);
                }
                u1[c] = s1; C1[c] = t1 + lin1_b[c] + ne_b[c];
                u2[c] = s2; C2[c] = t2 + lin2_b[c];
            }
            return;
        }
        int which = pb >> 4;
        const float* w = (which == 0) ? w11 : (which == 1) ? w12 : (which == 2) ? w21 : w22;
        int o = (pb & 15) * 1024 + threadIdx.x;   // 0..16383
        int j = o & 7;
        int lane = (o >> 3) & 63;
        int ct = (o >> 9) & 7;
        int ks = o >> 12;
        int k = ks * 32 + ((lane >> 4) * 8) + j;
        int c = ct * 16 + (lane & 15);
        float v = w[k * 128 + c];
        u16 h = f2bf(v);
        float vh = bf2f(h);
        u16 l = f2bf(v - vh);
        hi[which * 16384 + o] = h;
        lo[which * 16384 + o] = l;
        return;
    }

    // ---- bcount part ----
    __shared__ int h[256];
    __shared__ int is_last;
    if (threadIdx.x < 256) h[threadIdx.x] = 0;
    __syncthreads();
    int idx = blockIdx.x * 1024 + threadIdx.x;   // int4 index, covers 4 edges
    int e = idx * 4;
    if (e + 3 < E) {
        int4 d4 = ((const int4*)dst)[idx];
        atomicAdd(&h[d4.x >> 9], 1);
        atomicAdd(&h[d4.y >> 9], 1);
        atomicAdd(&h[d4.z >> 9], 1);
        atomicAdd(&h[d4.w >> 9], 1);
    } else {
        for (int k = e; k < E; ++k) atomicAdd(&h[dst[k] >> 9], 1);
    }
    __syncthreads();
    if (threadIdx.x < 256 && h[threadIdx.x]) atomicAdd(&bcnt[threadIdx.x], h[threadIdx.x]);
    __syncthreads();
    if (threadIdx.x == 0) {
        __threadfence();
        is_last = (atomicAdd(done, 1) == nbc - 1);
    }
    __syncthreads();
    if (!is_last) return;
    if (threadIdx.x < 256) h[threadIdx.x] = atomicAdd(&bcnt[threadIdx.x], 0);
    __syncthreads();
    __shared__ int excl[256];
    if (threadIdx.x < 64) {
        int l = threadIdx.x;
        int v0 = h[4 * l], v1 = h[4 * l + 1], v2 = h[4 * l + 2], v3 = h[4 * l + 3];
        int tot = v0 + v1 + v2 + v3;
        int run = tot;
#pragma unroll
        for (int off = 1; off < 64; off <<= 1) {
            int t = __shfl_up(run, off);
            if (l >= off) run += t;
        }
        int ex = run - tot;
        excl[4 * l] = ex;
        excl[4 * l + 1] = ex + v0;
        excl[4 * l + 2] = ex + v0 + v1;
        excl[4 * l + 3] = ex + v0 + v1 + v2;
    }
    __syncthreads();
    if (threadIdx.x < nb) {
        int ex = excl[threadIdx.x];
        bstart[threadIdx.x] = ex;
        bcur[threadIdx.x] = ex;
        if (threadIdx.x == nb - 1) bstart[nb] = ex + h[threadIdx.x];
    }
}

// block-local counting sort by bucket, coalesced run flush.
// record: x = src | (dst&511)<<17 (src < 2^17), y = attr bits
__global__ __launch_bounds__(1024) void bin_kernel(
    const int* __restrict__ src, const int* __restrict__ dst, const float* __restrict__ eattr,
    int* __restrict__ bucket_cursor,
    int2* __restrict__ binned, int E, int nb)
{
    __shared__ int hist[256];
    __shared__ int basel[256];
    __shared__ int gbase[256];
    __shared__ int2 stage[4096];
    __shared__ unsigned char sb[4096];
    const int tid = threadIdx.x;
    const int e0 = blockIdx.x * 4096;
    const int valid = min(4096, E - e0);

    if (tid < 256) hist[tid] = 0;
    __syncthreads();

    int d[4], s[4], a[4], rk[4];
    bool ok[4];
    const int eb = e0 + tid * 4;
    if (eb + 3 < E) {
        int4 d4 = *(const int4*)(dst + eb);
        int4 s4 = *(const int4*)(src + eb);
        int4 a4 = *(const int4*)((const int*)eattr + eb);
        d[0] = d4.x; d[1] = d4.y; d[2] = d4.z; d[3] = d4.w;
        s[0] = s4.x; s[1] = s4.y; s[2] = s4.z; s[3] = s4.w;
        a[0] = a4.x; a[1] = a4.y; a[2] = a4.z; a[3] = a4.w;
        ok[0] = ok[1] = ok[2] = ok[3] = true;
    } else {
#pragma unroll
        for (int k = 0; k < 4; ++k) {
            int e = eb + k;
            ok[k] = e < E;
            if (ok[k]) {
                d[k] = dst[e];
                s[k] = src[e];
                a[k] = __float_as_int(eattr[e]);
            }
        }
    }
#pragma unroll
    for (int k = 0; k < 4; ++k) {
        if (ok[k]) rk[k] = atomicAdd(&hist[d[k] >> 9], 1);
    }
    __syncthreads();
    if (tid < 64) {
        int l = tid;
        int v0 = hist[4 * l], v1 = hist[4 * l + 1], v2 = hist[4 * l + 2], v3 = hist[4 * l + 3];
        int tot = v0 + v1 + v2 + v3;
        int run = tot;
#pragma unroll
        for (int off = 1; off < 64; off <<= 1) {
            int t = __shfl_up(run, off);
            if (l >= off) run += t;
        }
        int ex = run - tot;
        basel[4 * l] = ex;
        basel[4 * l + 1] = ex + v0;
        basel[4 * l + 2] = ex + v0 + v1;
        basel[4 * l + 3] = ex + v0 + v1 + v2;
    }
    __syncthreads();
    if (tid < nb && hist[tid] > 0) gbase[tid] = atomicAdd(&bucket_cursor[tid], hist[tid]);
#pragma unroll
    for (int k = 0; k < 4; ++k) {
        if (ok[k]) {
            int b = d[k] >> 9;
            int pos = basel[b] + rk[k];
            stage[pos] = make_int2(s[k] | ((d[k] & 511) << 17), a[k]);
            sb[pos] = (unsigned char)b;
        }
    }
    __syncthreads();
    for (int i = tid; i < valid; i += 1024) {
        int b = (int)sb[i];
        binned[gbase[b] + (i - basel[b])] = stage[i];
    }
}

// One block per bucket: LDS histogram by dlo -> rowptr slice -> cursor scatter
__global__ __launch_bounds__(1024) void fine_kernel(
    const int2* __restrict__ binned, const int* __restrict__ bstart,
    int* __restrict__ rowptr, int2* __restrict__ edges, int N, int nbuckets)
{
    __shared__ int hist[512];
    __shared__ int excl[512];
    const int tid = threadIdx.x;
    const int b = blockIdx.x;
    const int s0 = bstart[b], s1 = bstart[b + 1];
    if (tid < 512) hist[tid] = 0;
    __syncthreads();
    for (int i = s0 + tid; i < s1; i += 1024)
        atomicAdd(&hist[(binned[i].x >> 17) & 511], 1);
    __syncthreads();
    if (tid < 64) {
        int l = tid;
        int v[8], pre[8];
        int tot = 0;
#pragma unroll
        for (int k = 0; k < 8; ++k) { v[k] = hist[8 * l + k]; pre[k] = tot; tot += v[k]; }
        int run = tot;
#pragma unroll
        for (int off = 1; off < 64; off <<= 1) {
            int t = __shfl_up(run, off);
            if (l >= off) run += t;
        }
        int ex = run - tot;
#pragma unroll
        for (int k = 0; k < 8; ++k) excl[8 * l + k] = ex + pre[k];
    }
    __syncthreads();
    const int nbase = b << 9;
    if (tid < 512 && nbase + tid < N) rowptr[nbase + tid] = s0 + excl[tid];
    if (b == nbuckets - 1 && tid == 0) rowptr[N] = s1;
    __syncthreads();
    for (int i = s0 + tid; i < s1; i += 1024) {
        int2 ed = binned[i];
        int dlo = (ed.x >> 17) & 511;
        ed.x &= 0x1FFFF;
        int pos = atomicAdd(&excl[dlo], 1);
        edges[s0 + pos] = ed;
    }
}

// ---------------- pull aggregation ----------------
// NOTE: pull kernels must stay separate from the MFMA MLP kernels (unified VGPR/AGPR
// file: fused kernel capped occupancy, BW 2.7 -> 1.17 TB/s, round 1).
//
// PULL2 IS AT ITS PRACTICAL ROOFLINE (rounds 5-10): FETCH 192 MB = per-XCD
// compulsory floor; random 256B-granule BW saturates ~3.0-3.1 TB/s at this
// structure (2 chains x 8-deep, readlane-broadcast records). Pinned from all
// sides: deeper batching spills (r6/r7: WRITE 25->180/62 MB); half-wave width
// split kills MLP concurrency (r10: record-load->gather vmcnt serialization,
// 2.07 TB/s); 32-bit saddr addressing neutral (r8: compiler already optimal).

__device__ __forceinline__ void p1_batch8(
    const float* __restrict__ x, const int2* __restrict__ edges, int j,
    f32x2 A, f32x2 Bv, f32x2 Cv, f32x2& acc)
{
    int2 ep = edges[j + (threadIdx.x & 7)];
    float xs[8], av[8];
#pragma unroll
    for (int t = 0; t < 8; ++t) {
        u32 s = (u32)__builtin_amdgcn_readlane(ep.x, t);
        av[t] = __int_as_float(__builtin_amdgcn_readlane(ep.y, t));
        xs[t] = *(const float*)((const char*)x + (s << 2));
    }
    const f32x2 zero = {0.f, 0.f};
#pragma unroll
    for (int t = 0; t < 8; ++t) {
        f32x2 m = __builtin_elementwise_fma((f32x2){xs[t], xs[t]}, A,
                    __builtin_elementwise_fma((f32x2){av[t], av[t]}, Bv, Cv));
        acc += __builtin_elementwise_max(m, zero);
    }
}

__device__ __forceinline__ void p1_batch8x2(
    const float* __restrict__ x, const int2* __restrict__ edges, int j0, int j1,
    f32x2 A, f32x2 Bv, f32x2 Cv, f32x2& acc0, f32x2& acc1)
{
    int2 ep0 = edges[j0 + (threadIdx.x & 7)];
    int2 ep1 = edges[j1 + (threadIdx.x & 7)];
    float xs0[8], av0[8], xs1[8], av1[8];
#pragma unroll
    for (int t = 0; t < 8; ++t) {
        u32 s = (u32)__builtin_amdgcn_readlane(ep0.x, t);
        av0[t] = __int_as_float(__builtin_amdgcn_readlane(ep0.y, t));
        xs0[t] = *(const float*)((const char*)x + (s << 2));
    }
#pragma unroll
    for (int t = 0; t < 8; ++t) {
        u32 s = (u32)__builtin_amdgcn_readlane(ep1.x, t);
        av1[t] = __int_as_float(__builtin_amdgcn_readlane(ep1.y, t));
        xs1[t] = *(const float*)((const char*)x + (s << 2));
    }
    const f32x2 zero = {0.f, 0.f};
#pragma unroll
    for (int t = 0; t < 8; ++t) {
        f32x2 m = __builtin_elementwise_fma((f32x2){xs0[t], xs0[t]}, A,
                    __builtin_elementwise_fma((f32x2){av0[t], av0[t]}, Bv, Cv));
        acc0 += __builtin_elementwise_max(m, zero);
    }
#pragma unroll
    for (int t = 0; t < 8; ++t) {
        f32x2 m = __builtin_elementwise_fma((f32x2){xs1[t], xs1[t]}, A,
                    __builtin_elementwise_fma((f32x2){av1[t], av1[t]}, Bv, Cv));
        acc1 += __builtin_elementwise_max(m, zero);
    }
}

__global__ __launch_bounds__(256) void pull1_kernel(
    const float* __restrict__ x,
    const int* __restrict__ rowptr, const int2* __restrict__ edges,
    const float* __restrict__ ne_w, const float* __restrict__ ne_b,
    const float* __restrict__ u1, const float* __restrict__ C1,
    u16* __restrict__ zb, int N)
{
    const int lane = threadIdx.x & 63;
    int pair = blockIdx.x * 4 + (threadIdx.x >> 6);
    int n0 = pair * 2;
    if (n0 >= N) return;
    const bool has1 = (n0 + 1 < N);
    f32x2 A   = *(const f32x2*)(ne_w + 2 * lane);
    f32x2 Bv  = *(const f32x2*)(u1   + 2 * lane);
    f32x2 Cv  = *(const f32x2*)(C1   + 2 * lane);
    f32x2 nbv = *(const f32x2*)(ne_b + 2 * lane);
    const f32x2 zero = {0.f, 0.f};
    int j0  = rowptr[n0];
    int je0 = rowptr[n0 + 1];
    int j1  = je0;
    int je1 = has1 ? rowptr[n0 + 2] : je0;
    // self terms: issue early (independent of the loop)
    float xn0 = x[n0];
    float xn1 = has1 ? x[n0 + 1] : 0.f;
    f32x2 acc0 = zero, acc1 = zero;
    while (j0 + 8 <= je0 && j1 + 8 <= je1) {
        p1_batch8x2(x, edges, j0, j1, A, Bv, Cv, acc0, acc1);
        j0 += 8; j1 += 8;
    }
    for (; j0 + 8 <= je0; j0 += 8) p1_batch8(x, edges, j0, A, Bv, Cv, acc0);
    for (; j1 + 8 <= je1; j1 += 8) p1_batch8(x, edges, j1, A, Bv, Cv, acc1);
    for (; j0 < je0; ++j0) {
        int2 ep = edges[j0];
        u32 s = (u32)__builtin_amdgcn_readfirstlane(ep.x);
        float av = __int_as_float(__builtin_amdgcn_readfirstlane(ep.y));
        float xs = *(const float*)((const char*)x + (s << 2));
        f32x2 m = __builtin_elementwise_fma((f32x2){xs, xs}, A,
                    __builtin_elementwise_fma((f32x2){av, av}, Bv, Cv));
        acc0 += __builtin_elementwise_max(m, zero);
    }
    for (; j1 < je1; ++j1) {
        int2 ep = edges[j1];
        u32 s = (u32)__builtin_amdgcn_readfirstlane(ep.x);
        float av = __int_as_float(__builtin_amdgcn_readfirstlane(ep.y));
        float xs = *(const float*)((const char*)x + (s << 2));
        f32x2 m = __builtin_elementwise_fma((f32x2){xs, xs}, A,
                    __builtin_elementwise_fma((f32x2){av, av}, Bv, Cv));
        acc1 += __builtin_elementwise_max(m, zero);
    }
    f32x2 z0 = __builtin_elementwise_fma((f32x2){xn0, xn0}, A, nbv) + acc0;
    ((u32*)(zb + (long)n0 * 128))[lane] = (u32)f2bf(z0.x) | ((u32)f2bf(z0.y) << 16);
    if (has1) {
        f32x2 z1 = __builtin_elementwise_fma((f32x2){xn1, xn1}, A, nbv) + acc1;
        ((u32*)(zb + (long)(n0 + 1) * 128))[lane] = (u32)f2bf(z1.x) | ((u32)f2bf(z1.y) << 16);
    }
}

__device__ __forceinline__ void p2_batch8(
    const u16* __restrict__ h1b, const int2* __restrict__ edges, int j,
    u32 loff, f32x2 Bv, f32x2 Cv, f32x2& acc)
{
    int2 ep = edges[j + (threadIdx.x & 7)];
    u32 hv[8];
    float av[8];
#pragma unroll
    for (int t = 0; t < 8; ++t) {
        u32 s = (u32)__builtin_amdgcn_readlane(ep.x, t);
        av[t] = __int_as_float(__builtin_amdgcn_readlane(ep.y, t));
        hv[t] = *(const u32*)((const char*)h1b + ((s << 8) | loff));
    }
    const f32x2 zero = {0.f, 0.f};
#pragma unroll
    for (int t = 0; t < 8; ++t) {
        f32x2 h = { __uint_as_float(hv[t] << 16), __uint_as_float(hv[t] & 0xFFFF0000u) };
        f32x2 m = h + __builtin_elementwise_fma((f32x2){av[t], av[t]}, Bv, Cv);
        acc += __builtin_elementwise_max(m, zero);
    }
}

__device__ __forceinline__ void p2_batch8x2(
    const u16* __restrict__ h1b, const int2* __restrict__ edges, int j0, int j1,
    u32 loff, f32x2 Bv, f32x2 Cv, f32x2& acc0, f32x2& acc1)
{
    int2 ep0 = edges[j0 + (threadIdx.x & 7)];
    int2 ep1 = edges[j1 + (threadIdx.x & 7)];
    u32 hv0[8], hv1[8];
    float av0[8], av1[8];
#pragma unroll
    for (int t = 0; t < 8; ++t) {
        u32 s = (u32)__builtin_amdgcn_readlane(ep0.x, t);
        av0[t] = __int_as_float(__builtin_amdgcn_readlane(ep0.y, t));
        hv0[t] = *(const u32*)((const char*)h1b + ((s << 8) | loff));
    }
#pragma unroll
    for (int t = 0; t < 8; ++t) {
        u32 s = (u32)__builtin_amdgcn_readlane(ep1.x, t);
        av1[t] = __int_as_float(__builtin_amdgcn_readlane(ep1.y, t));
        hv1[t] = *(const u32*)((const char*)h1b + ((s << 8) | loff));
    }
    const f32x2 zero = {0.f, 0.f};
#pragma unroll
    for (int t = 0; t < 8; ++t) {
        f32x2 h = { __uint_as_float(hv0[t] << 16), __uint_as_float(hv0[t] & 0xFFFF0000u) };
        f32x2 m = h + __builtin_elementwise_fma((f32x2){av0[t], av0[t]}, Bv, Cv);
        acc0 += __builtin_elementwise_max(m, zero);
    }
#pragma unroll
    for (int t = 0; t < 8; ++t) {
        f32x2 h = { __uint_as_float(hv1[t] << 16), __uint_as_float(hv1[t] & 0xFFFF0000u) };
        f32x2 m = h + __builtin_elementwise_fma((f32x2){av1[t], av1[t]}, Bv, Cv);
        acc1 += __builtin_elementwise_max(m, zero);
    }
}

__global__ __launch_bounds__(256) void pull2_kernel(
    const u16* __restrict__ h1b,
    const int* __restrict__ rowptr, const int2* __restrict__ edges,
    const float* __restrict__ u2, const float* __restrict__ C2,
    u16* __restrict__ zb2, int N)
{
    const int lane = threadIdx.x & 63;
    const int lane2 = 2 * lane;
    const u32 loff = (u32)lane2 * 2u;   // byte offset within a 256B row
    int pair = blockIdx.x * 4 + (threadIdx.x >> 6);
    int n0 = pair * 2;
    if (n0 >= N) return;
    const bool has1 = (n0 + 1 < N);
    f32x2 Bv = *(const f32x2*)(u2 + lane2);
    f32x2 Cv = *(const f32x2*)(C2 + lane2);
    const f32x2 zero = {0.f, 0.f};
    int j0  = rowptr[n0];
    int je0 = rowptr[n0 + 1];
    int j1  = je0;
    int je1 = has1 ? rowptr[n0 + 2] : je0;
    // self rows: issue early (independent of the loop)
    u32 hn0 = *(const u32*)((const char*)h1b + (((u32)n0 << 8) | loff));
    u32 hn1 = has1 ? *(const u32*)((const char*)h1b + (((u32)(n0 + 1) << 8) | loff)) : 0u;
    f32x2 acc0 = zero, acc1 = zero;
    while (j0 + 8 <= je0 && j1 + 8 <= je1) {
        p2_batch8x2(h1b, edges, j0, j1, loff, Bv, Cv, acc0, acc1);
        j0 += 8; j1 += 8;
    }
    for (; j0 + 8 <= je0; j0 += 8) p2_batch8(h1b, edges, j0, loff, Bv, Cv, acc0);
    for (; j1 + 8 <= je1; j1 += 8) p2_batch8(h1b, edges, j1, loff, Bv, Cv, acc1);
    for (; j0 < je0; ++j0) {
        int2 ep = edges[j0];
        u32 s = (u32)__builtin_amdgcn_readfirstlane(ep.x);
        float av = __int_as_float(__builtin_amdgcn_readfirstlane(ep.y));
        u32 hv = *(const u32*)((const char*)h1b + ((s << 8) | loff));
        f32x2 h = { __uint_as_float(hv << 16), __uint_as_float(hv & 0xFFFF0000u) };
        f32x2 m = h + __builtin_elementwise_fma((f32x2){av, av}, Bv, Cv);
        acc0 += __builtin_elementwise_max(m, zero);
    }
    for (; j1 < je1; ++j1) {
        int2 ep = edges[j1];
        u32 s = (u32)__builtin_amdgcn_readfirstlane(ep.x);
        float av = __int_as_float(__builtin_amdgcn_readfirstlane(ep.y));
        u32 hv = *(const u32*)((const char*)h1b + ((s << 8) | loff));
        f32x2 h = { __uint_as_float(hv << 16), __uint_as_float(hv & 0xFFFF0000u) };
        f32x2 m = h + __builtin_elementwise_fma((f32x2){av, av}, Bv, Cv);
        acc1 += __builtin_elementwise_max(m, zero);
    }
    f32x2 h0 = { __uint_as_float(hn0 << 16), __uint_as_float(hn0 & 0xFFFF0000u) };
    f32x2 z0 = h0 + acc0;
    ((u32*)(zb2 + (long)n0 * 128))[lane] = (u32)f2bf(z0.x) | ((u32)f2bf(z0.y) << 16);
    if (has1) {
        f32x2 h1 = { __uint_as_float(hn1 << 16), __uint_as_float(hn1 & 0xFFFF0000u) };
        f32x2 z1 = h1 + acc1;
        ((u32*)(zb2 + (long)(n0 + 1) * 128))[lane] = (u32)f2bf(z1.x) | ((u32)f2bf(z1.y) << 16);
    }
}

// ---------------- fused 2-GEMM node MLP (bf16 MFMA, split weights) ----------------
// Round-9 geometry: wave = 64 rows x 2 ct. Each bh/bl load feeds 8 MFMAs ->
// weight traffic 200 MB total across both MLP kernels (was 800). Accumulation
// order per output element unchanged (ks-outer, hi->lo) -> bit-identical.
__global__ __launch_bounds__(256) void mlp_kernel(
    const u16* __restrict__ zb,
    const u16* __restrict__ w1hi, const u16* __restrict__ w1lo,
    const u16* __restrict__ w2hi, const u16* __restrict__ w2lo,
    const float* __restrict__ b1, const float* __restrict__ b2,
    u16* __restrict__ outb)
{
    __shared__ __align__(16) u16 tls[64][136];
    const int lane = threadIdx.x & 63;
    const int wv = threadIdx.x >> 6;
    const int m = lane & 15;
    const int q = lane >> 4;
    const int ko = q * 8;
    const long base_row = (long)blockIdx.x * 64;
    const int ct0 = wv * 2;

    f32x4 acc[2][4];
#pragma unroll
    for (int c = 0; c < 2; ++c)
#pragma unroll
        for (int g = 0; g < 4; ++g) acc[c][g] = (f32x4){0.f, 0.f, 0.f, 0.f};

#pragma unroll
    for (int ks = 0; ks < 4; ++ks) {
        bfrag a[4];
#pragma unroll
        for (int g = 0; g < 4; ++g)
            a[g] = *(const bfrag*)(zb + (base_row + g * 16 + m) * 128 + ks * 32 + ko);
#pragma unroll
        for (int c = 0; c < 2; ++c) {
            const int off = (((ks * 8 + ct0 + c) * 64) + lane) * 8;
            bfrag bh = *(const bfrag*)(w1hi + off);
            bfrag bl = *(const bfrag*)(w1lo + off);
#pragma unroll
            for (int g = 0; g < 4; ++g)
                acc[c][g] = __builtin_amdgcn_mfma_f32_16x16x32_bf16(a[g], bh, acc[c][g], 0, 0, 0);
#pragma unroll
            for (int g = 0; g < 4; ++g)
                acc[c][g] = __builtin_amdgcn_mfma_f32_16x16x32_bf16(a[g], bl, acc[c][g], 0, 0, 0);
        }
    }
#pragma unroll
    for (int c = 0; c < 2; ++c) {
        float bv = b1[(ct0 + c) * 16 + m];
#pragma unroll
        for (int g = 0; g < 4; ++g)
#pragma unroll
            for (int r = 0; r < 4; ++r) {
                float v = fmaxf(acc[c][g][r] + bv, 0.f);
                tls[g * 16 + q * 4 + r][(ct0 + c) * 16 + m] = f2bf(v);
            }
    }
    __syncthreads();

    f32x4 acc2[2][4];
#pragma unroll
    for (int c = 0; c < 2; ++c)
#pragma unroll
        for (int g = 0; g < 4; ++g) acc2[c][g] = (f32x4){0.f, 0.f, 0.f, 0.f};

#pragma unroll
    for (int ks = 0; ks < 4; ++ks) {
        bfrag a[4];
#pragma unroll
        for (int g = 0; g < 4; ++g)
            a[g] = *(const bfrag*)(&tls[g * 16 + m][ks * 32 + ko]);
#pragma unroll
        for (int c = 0; c < 2; ++c) {
            const int off = (((ks * 8 + ct0 + c) * 64) + lane) * 8;
            bfrag bh = *(const bfrag*)(w2hi + off);
            bfrag bl = *(const bfrag*)(w2lo + off);
#pragma unroll
            for (int g = 0; g < 4; ++g)
                acc2[c][g] = __builtin_amdgcn_mfma_f32_16x16x32_bf16(a[g], bh, acc2[c][g], 0, 0, 0);
#pragma unroll
            for (int g = 0; g < 4; ++g)
                acc2[c][g] = __builtin_amdgcn_mfma_f32_16x16x32_bf16(a[g], bl, acc2[c][g], 0, 0, 0);
        }
    }
    __syncthreads();   // all waves done reading tls before overwrite
#pragma unroll
    for (int c = 0; c < 2; ++c) {
        float bv = b2[(ct0 + c) * 16 + m];
#pragma unroll
        for (int g = 0; g < 4; ++g)
#pragma unroll
            for (int r = 0; r < 4; ++r) {
                float v = fmaxf(acc2[c][g][r] + bv, 0.f);
                tls[g * 16 + q * 4 + r][(ct0 + c) * 16 + m] = f2bf(v);
            }
    }
    __syncthreads();
#pragma unroll
    for (int it = 0; it < 4; ++it) {
        int chunk = threadIdx.x + it * 256;   // 0..1023
        int row = chunk >> 4;
        int c8 = (chunk & 15) * 8;
        *(uint4*)(outb + (base_row + row) * 128 + c8) = *(const uint4*)(&tls[row][c8]);
    }
}

// Same MLP but final layer: no h2 global write — pool directly from LDS.
// Fire-and-forget pool atomics; blocks retire without draining (do NOT add a ticket here).
__global__ __launch_bounds__(256) void mlp_pool_kernel(
    const u16* __restrict__ zb,
    const u16* __restrict__ w1hi, const u16* __restrict__ w1lo,
    const u16* __restrict__ w2hi, const u16* __restrict__ w2lo,
    const float* __restrict__ b1, const float* __restrict__ b2,
    const int* __restrict__ batch, float* __restrict__ poolacc, int N)
{
    __shared__ __align__(16) u16 tls[64][136];
    __shared__ int bsh[64];
    const int lane = threadIdx.x & 63;
    const int wv = threadIdx.x >> 6;
    const int m = lane & 15;
    const int q = lane >> 4;
    const int ko = q * 8;
    const long base_row = (long)blockIdx.x * 64;
    const int ct0 = wv * 2;

    if (threadIdx.x < 64) {
        long node = base_row + threadIdx.x;
        bsh[threadIdx.x] = (node < N) ? batch[node] : -1;
    }

    f32x4 acc[2][4];
#pragma unroll
    for (int c = 0; c < 2; ++c)
#pragma unroll
        for (int g = 0; g < 4; ++g) acc[c][g] = (f32x4){0.f, 0.f, 0.f, 0.f};

#pragma unroll
    for (int ks = 0; ks < 4; ++ks) {
        bfrag a[4];
#pragma unroll
        for (int g = 0; g < 4; ++g)
            a[g] = *(const bfrag*)(zb + (base_row + g * 16 + m) * 128 + ks * 32 + ko);
#pragma unroll
        for (int c = 0; c < 2; ++c) {
            const int off = (((ks * 8 + ct0 + c) * 64) + lane) * 8;
            bfrag bh = *(const bfrag*)(w1hi + off);
            bfrag bl = *(const bfrag*)(w1lo + off);
#pragma unroll
            for (int g = 0; g < 4; ++g)
                acc[c][g] = __builtin_amdgcn_mfma_f32_16x16x32_bf16(a[g], bh, acc[c][g], 0, 0, 0);
#pragma unroll
            for (int g = 0; g < 4; ++g)
                acc[c][g] = __builtin_amdgcn_mfma_f32_16x16x32_bf16(a[g], bl, acc[c][g], 0, 0, 0);
        }
    }
#pragma unroll
    for (int c = 0; c < 2; ++c) {
        float bv = b1[(ct0 + c) * 16 + m];
#pragma unroll
        for (int g = 0; g < 4; ++g)
#pragma unroll
            for (int r = 0; r < 4; ++r) {
                float v = fmaxf(acc[c][g][r] + bv, 0.f);
                tls[g * 16 + q * 4 + r][(ct0 + c) * 16 + m] = f2bf(v);
            }
    }
    __syncthreads();

    f32x4 acc2[2][4];
#pragma unroll
    for (int c = 0; c < 2; ++c)
#pragma unroll
        for (int g = 0; g < 4; ++g) acc2[c][g] = (f32x4){0.f, 0.f, 0.f, 0.f};

#pragma unroll
    for (int ks = 0; ks < 4; ++ks) {
        bfrag a[4];
#pragma unroll
        for (int g = 0; g < 4; ++g)
            a[g] = *(const bfrag*)(&tls[g * 16 + m][ks * 32 + ko]);
#pragma unroll
        for (int c = 0; c < 2; ++c) {
            const int off = (((ks * 8 + ct0 + c) * 64) + lane) * 8;
            bfrag bh = *(const bfrag*)(w2hi + off);
            bfrag bl = *(const bfrag*)(w2lo + off);
#pragma unroll
            for (int g = 0; g < 4; ++g)
                acc2[c][g] = __builtin_amdgcn_mfma_f32_16x16x32_bf16(a[g], bh, acc2[c][g], 0, 0, 0);
#pragma unroll
            for (int g = 0; g < 4; ++g)
                acc2[c][g] = __builtin_amdgcn_mfma_f32_16x16x32_bf16(a[g], bl, acc2[c][g], 0, 0, 0);
        }
    }
    __syncthreads();   // tls reuse
#pragma unroll
    for (int c = 0; c < 2; ++c) {
        float bv = b2[(ct0 + c) * 16 + m];
#pragma unroll
        for (int g = 0; g < 4; ++g)
#pragma unroll
            for (int r = 0; r < 4; ++r) {
                float v = fmaxf(acc2[c][g][r] + bv, 0.f);
                tls[g * 16 + q * 4 + r][(ct0 + c) * 16 + m] = f2bf(v);
            }
    }
    __syncthreads();

    int c = threadIdx.x & 127;
    int half = threadIdx.x >> 7;
    int r0 = half * 32, r1 = r0 + 32;
    int cur = -1;
    float sum = 0.f;
    for (int r = r0; r < r1; ++r) {
        int g = bsh[r];
        if (g < 0) break;
        float v = bf2f((u32)tls[r][c]);
        if (g != cur) {
            if (cur >= 0) atomicAdd(&poolacc[cur * 128 + c], sum);
            sum = 0.f;
            cur = g;
        }
        sum += v;
    }
    if (cur >= 0) atomicAdd(&poolacc[cur * 128 + c], sum);
}

// divide by per-graph counts (binary search in sorted batch)
__global__ __launch_bounds__(128) void pool2_kernel(
    const float* __restrict__ acc, const int* __restrict__ batch,
    float* __restrict__ out, int n)
{
    int g = blockIdx.x;
    int c = threadIdx.x;
    int lo = 0, hi = n;
    while (lo < hi) { int mid = (lo + hi) >> 1; if (batch[mid] < g) lo = mid + 1; else hi = mid; }
    int s = lo;
    lo = s; hi = n;
    while (lo < hi) { int mid = (lo + hi) >> 1; if (batch[mid] < g + 1) lo = mid + 1; else hi = mid; }
    int cnt = lo - s;
    out[g * 128 + c] = acc[g * 128 + c] / (float)(cnt > 0 ? cnt : 1);
}

// ---------------- launch ----------------
extern "C" void kernel_launch(void* const* d_in, const int* in_sizes, int n_in,
                              void* d_out, int out_size, void* d_ws, size_t ws_size,
                              hipStream_t stream)
{
    const float* x      = (const float*)d_in[0];
    const int*   ei     = (const int*)d_in[1];
    const float* eattr  = (const float*)d_in[2];
    const int*   batch  = (const int*)d_in[3];
    const float* ne_w   = (const float*)d_in[4];
    const float* ne_b   = (const float*)d_in[5];
    const float* ee_w   = (const float*)d_in[6];
    const float* ee_b   = (const float*)d_in[7];
    const float* lin1_w = (const float*)d_in[8];
    const float* lin1_b = (const float*)d_in[9];
    const float* w11    = (const float*)d_in[10];
    const float* b11    = (const float*)d_in[11];
    const float* w12    = (const float*)d_in[12];
    const float* b12    = (const float*)d_in[13];
    const float* lin2_w = (const float*)d_in[14];
    const float* lin2_b = (const float*)d_in[15];
    const float* w21    = (const float*)d_in[16];
    const float* b21    = (const float*)d_in[17];
    const float* w22    = (const float*)d_in[18];
    const float* b22    = (const float*)d_in[19];

    const int N = in_sizes[0];
    const int E = in_sizes[2];
    const int G = out_size / 128;
    const int Npad = ((N + 63) / 64) * 64;
    const int nb = (N + 511) >> 9;     // 512-node buckets (<=256)
    const int nbc = (E + 4095) / 4096; // bcount/bin grid over edges
    const int* esrc = ei;
    const int* edst = ei + E;

    char* p = (char*)d_ws;
    auto alloc = [&](size_t bytes) -> void* {
        void* r = (void*)p;
        p += (bytes + 255) & ~(size_t)255;
        return r;
    };
    float* u1 = (float*)alloc(128 * 4);
    float* C1 = (float*)alloc(128 * 4);
    float* u2 = (float*)alloc(128 * 4);
    float* C2 = (float*)alloc(128 * 4);
    int* bcnt   = (int*)alloc(1024);
    int* done   = (int*)alloc(256);
    float* poolacc = (float*)alloc((size_t)G * 128 * 4);
    int* bstart = (int*)alloc(((size_t)nb + 1) * 4);
    int* bcur   = (int*)alloc((size_t)nb * 4);
    int* rowptr = (int*)alloc(((size_t)N + 1) * 4);
    int2* edges = (int2*)alloc((size_t)E * 8);
    int2* binned = (int2*)alloc((size_t)E * 8);
    u16* whi = (u16*)alloc((size_t)4 * 16384 * 2);
    u16* wlo = (u16*)alloc((size_t)4 * 16384 * 2);
    u16* bufA = (u16*)alloc((size_t)Npad * 128 * 2);
    u16* bufB = (u16*)alloc((size_t)Npad * 128 * 2);

    // one memset covers bcnt..done..poolacc (adjacent allocations)
    size_t zbytes = (size_t)((char*)poolacc + (size_t)G * 128 * 4 - (char*)bcnt);
    hipMemsetAsync(bcnt, 0, zbytes, stream);

    prepack_bcount_kernel<<<nbc + 65, 1024, 0, stream>>>(
        edst, bcnt, done, bstart, bcur, E, nb, nbc,
        w11, w12, w21, w22, whi, wlo,
        ne_b, ee_w, ee_b, lin1_w, lin1_b, lin2_w, lin2_b, u1, C1, u2, C2);

    bin_kernel<<<nbc, 1024, 0, stream>>>(esrc, edst, eattr, bcur, binned, E, nb);
    fine_kernel<<<nb, 1024, 0, stream>>>(binned, bstart, rowptr, edges, N, nb);

    pull1_kernel<<<(N + 7) / 8, 256, 0, stream>>>(x, rowptr, edges, ne_w, ne_b, u1, C1,
                                                  bufA, N);
    mlp_kernel<<<Npad / 64, 256, 0, stream>>>(bufA, whi, wlo, whi + 16384, wlo + 16384,
                                              b11, b12, bufB);
    pull2_kernel<<<(N + 7) / 8, 256, 0, stream>>>(bufB, rowptr, edges, u2, C2, bufA, N);
    mlp_pool_kernel<<<Npad / 64, 256, 0, stream>>>(bufA, whi + 32768, wlo + 32768,
                                                   whi + 49152, wlo + 49152, b21, b22,
                                                   batch, poolacc, N);

    pool2_kernel<<<G, 128, 0, stream>>>(poolacc, batch, (float*)d_out, N);
}